// Round 2
// baseline (4085.723 us; speedup 1.0000x reference)
//
#include <hip/hip_runtime.h>
#include <hip/hip_bf16.h>

// Problem constants: N=50000 nodes, E=800000 edges, D=128, F_IN=8, C=2
// Output: float32, [probs E*2 | bbox_pairs E*8 | bbox_index_pairs E*2]

// ---------------- degree / dinv ----------------
__global__ void k_deg_init(float* __restrict__ deg, int n) {
    int i = blockIdx.x * blockDim.x + threadIdx.x;
    if (i < n) deg[i] = 1.0f;  // self-loop
}

__global__ void k_deg_count(const int* __restrict__ col, float* __restrict__ deg, int E) {
    int e = blockIdx.x * blockDim.x + threadIdx.x;
    if (e < E) atomicAdd(&deg[col[e]], 1.0f);
}

__global__ void k_dinv(float* __restrict__ deg, int n) {
    int i = blockIdx.x * blockDim.x + threadIdx.x;
    if (i < n) deg[i] = rsqrtf(deg[i]);
}

// ---------------- layer-1 GEMM: h = feat[N,8] @ W1[8,128] ----------------
__global__ __launch_bounds__(256) void k_gemm_f8(const float* __restrict__ feat,
                                                 const float* __restrict__ W1,
                                                 float* __restrict__ h, int total) {
    int tid = blockIdx.x * blockDim.x + threadIdx.x;
    if (tid >= total) return;
    int n = tid >> 7, j = tid & 127;
    float acc = 0.f;
#pragma unroll
    for (int k = 0; k < 8; ++k) acc += feat[n * 8 + k] * W1[k * 128 + j];
    h[tid] = acc;
}

// ---------------- self-loop init: agg = h * dinv^2 ----------------
__global__ __launch_bounds__(256) void k_self_init(const float* __restrict__ h,
                                                   const float* __restrict__ dinv,
                                                   float* __restrict__ agg, int total) {
    int tid = blockIdx.x * blockDim.x + threadIdx.x;
    if (tid >= total) return;
    int n = tid >> 7;
    float d = dinv[n];
    agg[tid] = h[tid] * d * d;
}

// ---------------- scatter: agg[col] += h[row] * dinv[row]*dinv[col] ----------------
__global__ __launch_bounds__(256) void k_scatter(const float* __restrict__ h,
                                                 const float* __restrict__ dinv,
                                                 const int* __restrict__ row,
                                                 const int* __restrict__ col,
                                                 float* __restrict__ agg, int E) {
    int tid = blockIdx.x * blockDim.x + threadIdx.x;
    int e = tid >> 5;
    if (e >= E) return;
    int q = tid & 31;
    int r = row[e], c = col[e];
    float norm = dinv[r] * dinv[c];
    const float4 v = *reinterpret_cast<const float4*>(&h[(size_t)r * 128 + q * 4]);
    float* dst = &agg[(size_t)c * 128 + q * 4];
    atomicAdd(dst + 0, v.x * norm);
    atomicAdd(dst + 1, v.y * norm);
    atomicAdd(dst + 2, v.z * norm);
    atomicAdd(dst + 3, v.w * norm);
}

// ---------------- finalize: x = relu(agg + b) (in-place safe) ----------------
__global__ __launch_bounds__(256) void k_finalize(const float* __restrict__ agg,
                                                  const float* __restrict__ b,
                                                  float* __restrict__ x, int total) {
    int tid = blockIdx.x * blockDim.x + threadIdx.x;
    if (tid >= total) return;
    int j = tid & 127;
    x[tid] = fmaxf(agg[tid] + b[j], 0.f);
}

// ---------------- layer-2 GEMM: h = x[N,128] @ W[128,128], 16 nodes/block ----------------
__global__ __launch_bounds__(256) void k_gemm_128(const float* __restrict__ x,
                                                  const float* __restrict__ W,
                                                  float* __restrict__ h, int N) {
    __shared__ float xs[16 * 128];
    int n0 = blockIdx.x * 16;
    int tid = threadIdx.x;
    for (int idx = tid; idx < 16 * 128; idx += 256) {
        int n = n0 + (idx >> 7);
        xs[idx] = (n < N) ? x[(size_t)n0 * 128 + idx] : 0.f;
    }
    __syncthreads();
    int j = tid & 127, g = tid >> 7;
    float acc[8];
#pragma unroll
    for (int i = 0; i < 8; ++i) acc[i] = 0.f;
    for (int k = 0; k < 128; ++k) {
        float w = W[k * 128 + j];
#pragma unroll
        for (int i = 0; i < 8; ++i) acc[i] += xs[(g * 8 + i) * 128 + k] * w;
    }
#pragma unroll
    for (int i = 0; i < 8; ++i) {
        int n = n0 + g * 8 + i;
        if (n < N) h[(size_t)n * 128 + j] = acc[i];
    }
}

// ---------------- edge MLP + outputs ----------------
#define EB 64
__global__ __launch_bounds__(256) void k_edge_mlp(const float* __restrict__ x,
                                                  const float* __restrict__ lin1W,
                                                  const float* __restrict__ lin1b,
                                                  const float* __restrict__ linfW,
                                                  const float* __restrict__ linfb,
                                                  const float* __restrict__ bboxes,
                                                  const int* __restrict__ bidx,
                                                  const int* __restrict__ row,
                                                  const int* __restrict__ col,
                                                  float* __restrict__ out_probs,
                                                  float* __restrict__ out_bbox,
                                                  float* __restrict__ out_bidx,
                                                  int E) {
    __shared__ float xs[EB][32];        // gathered k-tile (8 KB)
    __shared__ float wsl[32 * 128];     // W k-tile (16 KB)
    __shared__ float hs[EB][129];       // hidden, padded (33 KB)
    __shared__ int esrc[EB], edst[EB];

    const int e0 = blockIdx.x * EB;
    const int tid = threadIdx.x;

    if (tid < EB) {
        int e = e0 + tid;
        esrc[tid] = (e < E) ? row[e] : 0;
    } else if (tid < 2 * EB) {
        int t = tid - EB;
        int e = e0 + t;
        edst[t] = (e < E) ? col[e] : 0;
    }
    __syncthreads();

    const int j4 = tid & 31;   // hidden group: j = j4*4 .. j4*4+3
    const int eg = tid >> 5;   // edge group: ee = eg*8 .. eg*8+7

    float acc[8][4];
#pragma unroll
    for (int i = 0; i < 8; ++i)
#pragma unroll
        for (int q = 0; q < 4; ++q) acc[i][q] = 0.f;

    for (int kt = 0; kt < 8; ++kt) {
        __syncthreads();  // protect xs/wsl from previous iteration's readers
#pragma unroll
        for (int r = 0; r < 16; ++r) {
            int idx = r * 256 + tid;
            wsl[idx] = lin1W[kt * 4096 + idx];
        }
        {
            int kk = tid & 31;
            int eb = tid >> 5;
#pragma unroll
            for (int p = 0; p < 8; ++p) {
                int ee = p * 8 + eb;
                int node = (kt < 4) ? esrc[ee] : edst[ee];
                int koff = (kt & 3) * 32 + kk;
                xs[ee][kk] = x[(size_t)node * 128 + koff];
            }
        }
        __syncthreads();
#pragma unroll
        for (int kk = 0; kk < 32; ++kk) {
            const float4 w = *reinterpret_cast<const float4*>(&wsl[kk * 128 + j4 * 4]);
#pragma unroll
            for (int i = 0; i < 8; ++i) {
                float xv = xs[eg * 8 + i][kk];
                acc[i][0] += xv * w.x;
                acc[i][1] += xv * w.y;
                acc[i][2] += xv * w.z;
                acc[i][3] += xv * w.w;
            }
        }
    }

    // bias + relu -> hs
#pragma unroll
    for (int i = 0; i < 8; ++i) {
        int ee = eg * 8 + i;
#pragma unroll
        for (int q = 0; q < 4; ++q) {
            float v = acc[i][q] + lin1b[j4 * 4 + q];
            hs[ee][j4 * 4 + q] = fmaxf(v, 0.f);
        }
    }
    __syncthreads();

    // logits + log_softmax (2 classes): threads 0..127 -> (edge, class)
    if (tid < 128) {
        int ee = tid >> 1, c = tid & 1;
        float z = linfb[c];
#pragma unroll 8
        for (int k = 0; k < 128; ++k) z += hs[ee][k] * linfW[k * 2 + c];
        float zo = __shfl_xor(z, 1);
        float m = fmaxf(z, zo);
        float lse = m + logf(expf(z - m) + expf(zo - m));
        int e = e0 + ee;
        if (e < E) out_probs[(size_t)e * 2 + c] = z - lse;
    }

    // bbox_pairs: [E,8] = concat(bboxes[src], bboxes[dst])
    for (int idx = tid; idx < EB * 8; idx += 256) {
        int ee = idx >> 3, q = idx & 7;
        int e = e0 + ee;
        if (e < E) {
            int node = (q < 4) ? esrc[ee] : edst[ee];
            out_bbox[(size_t)e * 8 + q] = bboxes[(size_t)node * 4 + (q & 3)];
        }
    }
    // bbox_index_pairs: [E,2] (write index values as float32)
    for (int idx = tid; idx < EB * 2; idx += 256) {
        int ee = idx >> 1, c = idx & 1;
        int e = e0 + ee;
        if (e < E) {
            int node = c ? edst[ee] : esrc[ee];
            out_bidx[(size_t)e * 2 + c] = (float)bidx[node];
        }
    }
}

extern "C" void kernel_launch(void* const* d_in, const int* in_sizes, int n_in,
                              void* d_out, int out_size, void* d_ws, size_t ws_size,
                              hipStream_t stream) {
    const float* feat   = (const float*)d_in[0];
    const float* bboxes = (const float*)d_in[1];
    const int*   bidx   = (const int*)d_in[2];
    const int*   eidx   = (const int*)d_in[3];
    const float* W1     = (const float*)d_in[4];
    const float* b1     = (const float*)d_in[5];
    const float* W2     = (const float*)d_in[6];
    const float* b2     = (const float*)d_in[7];
    const float* lin1W  = (const float*)d_in[8];
    const float* lin1b  = (const float*)d_in[9];
    const float* linfW  = (const float*)d_in[10];
    const float* linfb  = (const float*)d_in[11];

    const int N = in_sizes[0] / 8;
    const int E = in_sizes[3] / 2;
    const int* row = eidx;        // sources
    const int* col = eidx + E;    // targets

    // workspace layout
    float* deg  = (float*)d_ws;                        // N (becomes dinv)
    float* bufA = deg + (((size_t)N + 255) & ~255ull); // N*128
    float* bufB = bufA + (size_t)N * 128;              // N*128

    float* out       = (float*)d_out;
    float* out_probs = out;                   // E*2
    float* out_bbox  = out + (size_t)E * 2;   // E*8
    float* out_bidx  = out + (size_t)E * 10;  // E*2

    const int total = N * 128;
    const int B = 256;

    // degree -> dinv
    k_deg_init<<<(N + B - 1) / B, B, 0, stream>>>(deg, N);
    k_deg_count<<<(E + B - 1) / B, B, 0, stream>>>(col, deg, E);
    k_dinv<<<(N + B - 1) / B, B, 0, stream>>>(deg, N);

    // layer 1
    k_gemm_f8<<<(total + B - 1) / B, B, 0, stream>>>(feat, W1, bufA, total);
    k_self_init<<<(total + B - 1) / B, B, 0, stream>>>(bufA, deg, bufB, total);
    k_scatter<<<((size_t)E * 32 + B - 1) / B, B, 0, stream>>>(bufA, deg, row, col, bufB, E);
    k_finalize<<<(total + B - 1) / B, B, 0, stream>>>(bufB, b1, bufB, total);

    // layer 2
    k_gemm_128<<<(N + 15) / 16, B, 0, stream>>>(bufB, W2, bufA, N);
    k_self_init<<<(total + B - 1) / B, B, 0, stream>>>(bufA, deg, bufB, total);
    k_scatter<<<((size_t)E * 32 + B - 1) / B, B, 0, stream>>>(bufA, deg, row, col, bufB, E);
    k_finalize<<<(total + B - 1) / B, B, 0, stream>>>(bufB, b2, bufB, total);

    // edge MLP + outputs
    k_edge_mlp<<<(E + EB - 1) / EB, B, 0, stream>>>(bufB, lin1W, lin1b, linfW, linfb,
                                                    bboxes, bidx, row, col,
                                                    out_probs, out_bbox, out_bidx, E);
}

// Round 3
// 1489.356 us; speedup vs baseline: 2.7433x; 2.7433x over previous
//
#include <hip/hip_runtime.h>
#include <hip/hip_bf16.h>

// N=50000 nodes, E=800000 edges, D=128, F_IN=8, C=2
// Output float32: [probs E*2 | bbox_pairs E*8 | bbox_index_pairs E*2]

// ---------------- CSR build ----------------
__global__ void k_zero(int* __restrict__ p, int n) {
    int i = blockIdx.x * blockDim.x + threadIdx.x;
    if (i < n) p[i] = 0;
}

__global__ void k_hist(const int* __restrict__ col, int* __restrict__ cnt, int E) {
    int e = blockIdx.x * blockDim.x + threadIdx.x;
    if (e < E) atomicAdd(&cnt[col[e]], 1);
}

// single-block exclusive scan: cnt[N] -> ptr[N+1]
__global__ __launch_bounds__(1024) void k_scan(const int* __restrict__ cnt,
                                               int* __restrict__ ptr, int N) {
    __shared__ int sums[1024];
    int tid = threadIdx.x;
    int chunk = (N + 1023) / 1024;
    int lo = tid * chunk;
    int hi = min(lo + chunk, N);
    int s = 0;
    for (int i = lo; i < hi; ++i) s += cnt[i];
    sums[tid] = s;
    __syncthreads();
    for (int off = 1; off < 1024; off <<= 1) {
        int v = (tid >= off) ? sums[tid - off] : 0;
        __syncthreads();
        sums[tid] += v;
        __syncthreads();
    }
    int run = (tid > 0) ? sums[tid - 1] : 0;
    for (int i = lo; i < hi; ++i) { ptr[i] = run; run += cnt[i]; }
    if (tid == 1023) ptr[N] = run;
}

// dinv = rsqrt(1 + in-degree)
__global__ void k_dinv(const int* __restrict__ cnt, float* __restrict__ dinv, int n) {
    int i = blockIdx.x * blockDim.x + threadIdx.x;
    if (i < n) dinv[i] = rsqrtf(1.0f + (float)cnt[i]);
}

__global__ void k_fill(const int* __restrict__ row, const int* __restrict__ col,
                       const float* __restrict__ dinv, const int* __restrict__ ptr,
                       int* __restrict__ cursor, int* __restrict__ esrc,
                       float* __restrict__ enorm, int E) {
    int e = blockIdx.x * blockDim.x + threadIdx.x;
    if (e >= E) return;
    int r = row[e], c = col[e];
    int p = ptr[c] + atomicAdd(&cursor[c], 1);
    esrc[p] = r;
    enorm[p] = dinv[r] * dinv[c];
}

// ---------------- layer-1 GEMM: h = feat[N,8] @ W1[8,128] ----------------
__global__ __launch_bounds__(256) void k_gemm_f8(const float* __restrict__ feat,
                                                 const float* __restrict__ W1,
                                                 float* __restrict__ h, int total) {
    int tid = blockIdx.x * blockDim.x + threadIdx.x;
    if (tid >= total) return;
    int n = tid >> 7, j = tid & 127;
    float acc = 0.f;
#pragma unroll
    for (int k = 0; k < 8; ++k) acc += feat[n * 8 + k] * W1[k * 128 + j];
    h[tid] = acc;
}

// ---------------- fused aggregate: out = relu(h[n]*dinv^2 + sum_in h[s]*norm + b) ----------------
__global__ __launch_bounds__(256) void k_gather(const float* __restrict__ h,
                                                const float* __restrict__ dinv,
                                                const int* __restrict__ ptr,
                                                const int* __restrict__ esrc,
                                                const float* __restrict__ enorm,
                                                const float* __restrict__ b,
                                                float* __restrict__ out, int N) {
    int g = threadIdx.x >> 5;                 // 8 node-groups per block
    int q = threadIdx.x & 31;                 // float4 slot
    int node = blockIdx.x * 8 + g;
    if (node >= N) return;
    float d = dinv[node];
    float4 acc = *reinterpret_cast<const float4*>(&h[(size_t)node * 128 + q * 4]);
    float dd = d * d;
    acc.x *= dd; acc.y *= dd; acc.z *= dd; acc.w *= dd;
    int i = ptr[node], end = ptr[node + 1];
    for (; i + 1 < end; i += 2) {
        int s0 = esrc[i], s1 = esrc[i + 1];
        float n0 = enorm[i], n1 = enorm[i + 1];
        const float4 v0 = *reinterpret_cast<const float4*>(&h[(size_t)s0 * 128 + q * 4]);
        const float4 v1 = *reinterpret_cast<const float4*>(&h[(size_t)s1 * 128 + q * 4]);
        acc.x += v0.x * n0 + v1.x * n1;
        acc.y += v0.y * n0 + v1.y * n1;
        acc.z += v0.z * n0 + v1.z * n1;
        acc.w += v0.w * n0 + v1.w * n1;
    }
    if (i < end) {
        int s0 = esrc[i];
        float n0 = enorm[i];
        const float4 v0 = *reinterpret_cast<const float4*>(&h[(size_t)s0 * 128 + q * 4]);
        acc.x += v0.x * n0; acc.y += v0.y * n0; acc.z += v0.z * n0; acc.w += v0.w * n0;
    }
    const float4 bb = *reinterpret_cast<const float4*>(&b[q * 4]);
    float4 r;
    r.x = fmaxf(acc.x + bb.x, 0.f);
    r.y = fmaxf(acc.y + bb.y, 0.f);
    r.z = fmaxf(acc.z + bb.z, 0.f);
    r.w = fmaxf(acc.w + bb.w, 0.f);
    *reinterpret_cast<float4*>(&out[(size_t)node * 128 + q * 4]) = r;
}

// ---------------- layer-2 GEMM: h = x[N,128] @ W[128,128], 16 nodes/block ----------------
__global__ __launch_bounds__(256) void k_gemm_128(const float* __restrict__ x,
                                                  const float* __restrict__ W,
                                                  float* __restrict__ h, int N) {
    __shared__ float xs[16 * 128];
    int n0 = blockIdx.x * 16;
    int tid = threadIdx.x;
    for (int idx = tid; idx < 16 * 128; idx += 256) {
        int n = n0 + (idx >> 7);
        xs[idx] = (n < N) ? x[(size_t)n0 * 128 + idx] : 0.f;
    }
    __syncthreads();
    int j = tid & 127, g = tid >> 7;
    float acc[8];
#pragma unroll
    for (int i = 0; i < 8; ++i) acc[i] = 0.f;
    for (int k = 0; k < 128; ++k) {
        float w = W[k * 128 + j];
#pragma unroll
        for (int i = 0; i < 8; ++i) acc[i] += xs[(g * 8 + i) * 128 + k] * w;
    }
#pragma unroll
    for (int i = 0; i < 8; ++i) {
        int n = n0 + g * 8 + i;
        if (n < N) h[(size_t)n * 128 + j] = acc[i];
    }
}

// ---------------- edge MLP + outputs ----------------
#define EB 64
__global__ __launch_bounds__(256) void k_edge_mlp(const float* __restrict__ x,
                                                  const float* __restrict__ lin1W,
                                                  const float* __restrict__ lin1b,
                                                  const float* __restrict__ linfW,
                                                  const float* __restrict__ linfb,
                                                  const float* __restrict__ bboxes,
                                                  const int* __restrict__ bidx,
                                                  const int* __restrict__ row,
                                                  const int* __restrict__ col,
                                                  float* __restrict__ out_probs,
                                                  float* __restrict__ out_bbox,
                                                  float* __restrict__ out_bidx,
                                                  int E) {
    __shared__ float xs[EB][32];
    __shared__ float wsl[32 * 128];
    __shared__ float hs[EB][129];
    __shared__ int esrc[EB], edst[EB];

    const int e0 = blockIdx.x * EB;
    const int tid = threadIdx.x;

    if (tid < EB) {
        int e = e0 + tid;
        esrc[tid] = (e < E) ? row[e] : 0;
    } else if (tid < 2 * EB) {
        int t = tid - EB;
        int e = e0 + t;
        edst[t] = (e < E) ? col[e] : 0;
    }
    __syncthreads();

    const int j4 = tid & 31;
    const int eg = tid >> 5;

    float acc[8][4];
#pragma unroll
    for (int i = 0; i < 8; ++i)
#pragma unroll
        for (int q = 0; q < 4; ++q) acc[i][q] = 0.f;

    for (int kt = 0; kt < 8; ++kt) {
        __syncthreads();
#pragma unroll
        for (int r = 0; r < 16; ++r) {
            int idx = r * 256 + tid;
            wsl[idx] = lin1W[kt * 4096 + idx];
        }
        {
            int kk = tid & 31;
            int eb = tid >> 5;
#pragma unroll
            for (int p = 0; p < 8; ++p) {
                int ee = p * 8 + eb;
                int node = (kt < 4) ? esrc[ee] : edst[ee];
                int koff = (kt & 3) * 32 + kk;
                xs[ee][kk] = x[(size_t)node * 128 + koff];
            }
        }
        __syncthreads();
#pragma unroll
        for (int kk = 0; kk < 32; ++kk) {
            const float4 w = *reinterpret_cast<const float4*>(&wsl[kk * 128 + j4 * 4]);
#pragma unroll
            for (int i = 0; i < 8; ++i) {
                float xv = xs[eg * 8 + i][kk];
                acc[i][0] += xv * w.x;
                acc[i][1] += xv * w.y;
                acc[i][2] += xv * w.z;
                acc[i][3] += xv * w.w;
            }
        }
    }

#pragma unroll
    for (int i = 0; i < 8; ++i) {
        int ee = eg * 8 + i;
#pragma unroll
        for (int q = 0; q < 4; ++q) {
            float v = acc[i][q] + lin1b[j4 * 4 + q];
            hs[ee][j4 * 4 + q] = fmaxf(v, 0.f);
        }
    }
    __syncthreads();

    if (tid < 128) {
        int ee = tid >> 1, c = tid & 1;
        float z = linfb[c];
#pragma unroll 8
        for (int k = 0; k < 128; ++k) z += hs[ee][k] * linfW[k * 2 + c];
        float zo = __shfl_xor(z, 1);
        float m = fmaxf(z, zo);
        float lse = m + logf(expf(z - m) + expf(zo - m));
        int e = e0 + ee;
        if (e < E) out_probs[(size_t)e * 2 + c] = z - lse;
    }

    for (int idx = tid; idx < EB * 8; idx += 256) {
        int ee = idx >> 3, q = idx & 7;
        int e = e0 + ee;
        if (e < E) {
            int node = (q < 4) ? esrc[ee] : edst[ee];
            out_bbox[(size_t)e * 8 + q] = bboxes[(size_t)node * 4 + (q & 3)];
        }
    }
    for (int idx = tid; idx < EB * 2; idx += 256) {
        int ee = idx >> 1, c = idx & 1;
        int e = e0 + ee;
        if (e < E) {
            int node = c ? edst[ee] : esrc[ee];
            out_bidx[(size_t)e * 2 + c] = (float)bidx[node];
        }
    }
}

extern "C" void kernel_launch(void* const* d_in, const int* in_sizes, int n_in,
                              void* d_out, int out_size, void* d_ws, size_t ws_size,
                              hipStream_t stream) {
    const float* feat   = (const float*)d_in[0];
    const float* bboxes = (const float*)d_in[1];
    const int*   bidx   = (const int*)d_in[2];
    const int*   eidx   = (const int*)d_in[3];
    const float* W1     = (const float*)d_in[4];
    const float* b1     = (const float*)d_in[5];
    const float* W2     = (const float*)d_in[6];
    const float* b2     = (const float*)d_in[7];
    const float* lin1W  = (const float*)d_in[8];
    const float* lin1b  = (const float*)d_in[9];
    const float* linfW  = (const float*)d_in[10];
    const float* linfb  = (const float*)d_in[11];

    const int N = in_sizes[0] / 8;
    const int E = in_sizes[3] / 2;
    const int* row = eidx;        // sources
    const int* col = eidx + E;    // targets

    // workspace layout (floats/ints are 4B each)
    size_t Np = ((size_t)N + 255) & ~255ull;
    size_t Ep = ((size_t)E + 255) & ~255ull;
    int*   cnt    = (int*)d_ws;                 // Np
    int*   cursor = cnt + Np;                   // Np
    int*   ptr    = cursor + Np;                // Np+256 (N+1 used)
    float* dinv   = (float*)(ptr + Np + 256);   // Np
    int*   esrc   = (int*)(dinv + Np);          // Ep
    float* enorm  = (float*)(esrc + Ep);        // Ep
    float* bufA   = enorm + Ep;                 // N*128
    float* bufB   = bufA + (size_t)N * 128;     // N*128

    float* out       = (float*)d_out;
    float* out_probs = out;                   // E*2
    float* out_bbox  = out + (size_t)E * 2;   // E*8
    float* out_bidx  = out + (size_t)E * 10;  // E*2

    const int total = N * 128;
    const int B = 256;

    // CSR build (by destination) + dinv
    k_zero<<<(int)((2 * Np + B - 1) / B), B, 0, stream>>>(cnt, (int)(2 * Np));
    k_hist<<<(E + B - 1) / B, B, 0, stream>>>(col, cnt, E);
    k_scan<<<1, 1024, 0, stream>>>(cnt, ptr, N);
    k_dinv<<<(N + B - 1) / B, B, 0, stream>>>(cnt, dinv, N);
    k_fill<<<(E + B - 1) / B, B, 0, stream>>>(row, col, dinv, ptr, cursor, esrc, enorm, E);

    // layer 1: h = feat @ W1 ; x1 = relu(D^-1/2 A D^-1/2 h + b1)
    k_gemm_f8<<<(total + B - 1) / B, B, 0, stream>>>(feat, W1, bufA, total);
    k_gather<<<(N + 7) / 8, B, 0, stream>>>(bufA, dinv, ptr, esrc, enorm, b1, bufB, N);

    // layer 2
    k_gemm_128<<<(N + 15) / 16, B, 0, stream>>>(bufB, W2, bufA, N);
    k_gather<<<(N + 7) / 8, B, 0, stream>>>(bufA, dinv, ptr, esrc, enorm, b2, bufB, N);

    // edge MLP + outputs
    k_edge_mlp<<<(E + EB - 1) / EB, B, 0, stream>>>(bufB, lin1W, lin1b, linfW, linfb,
                                                    bboxes, bidx, row, col,
                                                    out_probs, out_bbox, out_bidx, E);
}

// Round 4
// 749.862 us; speedup vs baseline: 5.4486x; 1.9862x over previous
//
#include <hip/hip_runtime.h>
#include <hip/hip_bf16.h>

// N=50000 nodes, E=800000 edges, D=128, F_IN=8, C=2
// Output float32: [probs E*2 | bbox_pairs E*8 | bbox_index_pairs E*2]

typedef __attribute__((ext_vector_type(8))) short short8;
typedef __attribute__((ext_vector_type(4))) float f32x4;

__device__ inline ushort f2bf(float f) {
    union { __hip_bfloat16 h; ushort u; } cv;
    cv.h = __float2bfloat16(f);
    return cv.u;
}

// ---------------- CSR build ----------------
__global__ void k_zero(int* __restrict__ p, int n) {
    int i = blockIdx.x * blockDim.x + threadIdx.x;
    if (i < n) p[i] = 0;
}

__global__ void k_hist(const int* __restrict__ col, int* __restrict__ cnt, int E) {
    int e = blockIdx.x * blockDim.x + threadIdx.x;
    if (e < E) atomicAdd(&cnt[col[e]], 1);
}

__global__ __launch_bounds__(1024) void k_scan(const int* __restrict__ cnt,
                                               int* __restrict__ ptr, int N) {
    __shared__ int sums[1024];
    int tid = threadIdx.x;
    int chunk = (N + 1023) / 1024;
    int lo = tid * chunk;
    int hi = min(lo + chunk, N);
    int s = 0;
    for (int i = lo; i < hi; ++i) s += cnt[i];
    sums[tid] = s;
    __syncthreads();
    for (int off = 1; off < 1024; off <<= 1) {
        int v = (tid >= off) ? sums[tid - off] : 0;
        __syncthreads();
        sums[tid] += v;
        __syncthreads();
    }
    int run = (tid > 0) ? sums[tid - 1] : 0;
    for (int i = lo; i < hi; ++i) { ptr[i] = run; run += cnt[i]; }
    if (tid == 1023) ptr[N] = run;
}

__global__ void k_dinv(const int* __restrict__ cnt, float* __restrict__ dinv, int n) {
    int i = blockIdx.x * blockDim.x + threadIdx.x;
    if (i < n) dinv[i] = rsqrtf(1.0f + (float)cnt[i]);
}

__global__ void k_fill(const int* __restrict__ row, const int* __restrict__ col,
                       const float* __restrict__ dinv, const int* __restrict__ ptr,
                       int* __restrict__ cursor, int* __restrict__ esrc,
                       float* __restrict__ enorm, int E) {
    int e = blockIdx.x * blockDim.x + threadIdx.x;
    if (e >= E) return;
    int r = row[e], c = col[e];
    int p = ptr[c] + atomicAdd(&cursor[c], 1);
    esrc[p] = r;
    enorm[p] = dinv[r] * dinv[c];
}

// ---------------- weight prep: Wt[n][k] = bf16(lin1W[k][n]) ----------------
__global__ void k_prepW(const float* __restrict__ W, ushort* __restrict__ Wt) {
    int tid = blockIdx.x * blockDim.x + threadIdx.x;
    if (tid >= 128 * 256) return;
    int n = tid >> 8, k = tid & 255;
    Wt[tid] = f2bf(W[k * 128 + n]);
}

// ---------------- layer-1 GEMM: h = feat[N,8] @ W1[8,128] ----------------
__global__ __launch_bounds__(256) void k_gemm_f8(const float* __restrict__ feat,
                                                 const float* __restrict__ W1,
                                                 float* __restrict__ h, int total) {
    int tid = blockIdx.x * blockDim.x + threadIdx.x;
    if (tid >= total) return;
    int n = tid >> 7, j = tid & 127;
    float acc = 0.f;
#pragma unroll
    for (int k = 0; k < 8; ++k) acc += feat[n * 8 + k] * W1[k * 128 + j];
    h[tid] = acc;
}

// ---------------- fused aggregate (fp32 out): relu(h[n]*dinv^2 + sum h[s]*norm + b) ----------------
__global__ __launch_bounds__(256) void k_gather(const float* __restrict__ h,
                                                const float* __restrict__ dinv,
                                                const int* __restrict__ ptr,
                                                const int* __restrict__ esrc,
                                                const float* __restrict__ enorm,
                                                const float* __restrict__ b,
                                                float* __restrict__ out, int N) {
    int g = threadIdx.x >> 5;
    int q = threadIdx.x & 31;
    int node = blockIdx.x * 8 + g;
    if (node >= N) return;
    float d = dinv[node];
    float4 acc = *reinterpret_cast<const float4*>(&h[(size_t)node * 128 + q * 4]);
    float dd = d * d;
    acc.x *= dd; acc.y *= dd; acc.z *= dd; acc.w *= dd;
    int i = ptr[node], end = ptr[node + 1];
    for (; i + 1 < end; i += 2) {
        int s0 = esrc[i], s1 = esrc[i + 1];
        float n0 = enorm[i], n1 = enorm[i + 1];
        const float4 v0 = *reinterpret_cast<const float4*>(&h[(size_t)s0 * 128 + q * 4]);
        const float4 v1 = *reinterpret_cast<const float4*>(&h[(size_t)s1 * 128 + q * 4]);
        acc.x += v0.x * n0 + v1.x * n1;
        acc.y += v0.y * n0 + v1.y * n1;
        acc.z += v0.z * n0 + v1.z * n1;
        acc.w += v0.w * n0 + v1.w * n1;
    }
    if (i < end) {
        int s0 = esrc[i];
        float n0 = enorm[i];
        const float4 v0 = *reinterpret_cast<const float4*>(&h[(size_t)s0 * 128 + q * 4]);
        acc.x += v0.x * n0; acc.y += v0.y * n0; acc.z += v0.z * n0; acc.w += v0.w * n0;
    }
    const float4 bb = *reinterpret_cast<const float4*>(&b[q * 4]);
    float4 r;
    r.x = fmaxf(acc.x + bb.x, 0.f);
    r.y = fmaxf(acc.y + bb.y, 0.f);
    r.z = fmaxf(acc.z + bb.z, 0.f);
    r.w = fmaxf(acc.w + bb.w, 0.f);
    *reinterpret_cast<float4*>(&out[(size_t)node * 128 + q * 4]) = r;
}

// ---------------- fused aggregate (bf16 out) ----------------
__global__ __launch_bounds__(256) void k_gather_bf(const float* __restrict__ h,
                                                   const float* __restrict__ dinv,
                                                   const int* __restrict__ ptr,
                                                   const int* __restrict__ esrc,
                                                   const float* __restrict__ enorm,
                                                   const float* __restrict__ b,
                                                   ushort* __restrict__ out, int N) {
    int g = threadIdx.x >> 5;
    int q = threadIdx.x & 31;
    int node = blockIdx.x * 8 + g;
    if (node >= N) return;
    float d = dinv[node];
    float4 acc = *reinterpret_cast<const float4*>(&h[(size_t)node * 128 + q * 4]);
    float dd = d * d;
    acc.x *= dd; acc.y *= dd; acc.z *= dd; acc.w *= dd;
    int i = ptr[node], end = ptr[node + 1];
    for (; i + 1 < end; i += 2) {
        int s0 = esrc[i], s1 = esrc[i + 1];
        float n0 = enorm[i], n1 = enorm[i + 1];
        const float4 v0 = *reinterpret_cast<const float4*>(&h[(size_t)s0 * 128 + q * 4]);
        const float4 v1 = *reinterpret_cast<const float4*>(&h[(size_t)s1 * 128 + q * 4]);
        acc.x += v0.x * n0 + v1.x * n1;
        acc.y += v0.y * n0 + v1.y * n1;
        acc.z += v0.z * n0 + v1.z * n1;
        acc.w += v0.w * n0 + v1.w * n1;
    }
    if (i < end) {
        int s0 = esrc[i];
        float n0 = enorm[i];
        const float4 v0 = *reinterpret_cast<const float4*>(&h[(size_t)s0 * 128 + q * 4]);
        acc.x += v0.x * n0; acc.y += v0.y * n0; acc.z += v0.z * n0; acc.w += v0.w * n0;
    }
    const float4 bb = *reinterpret_cast<const float4*>(&b[q * 4]);
    ushort4 r;
    r.x = f2bf(fmaxf(acc.x + bb.x, 0.f));
    r.y = f2bf(fmaxf(acc.y + bb.y, 0.f));
    r.z = f2bf(fmaxf(acc.z + bb.z, 0.f));
    r.w = f2bf(fmaxf(acc.w + bb.w, 0.f));
    *reinterpret_cast<ushort4*>(&out[(size_t)node * 128 + q * 4]) = r;
}

// ---------------- layer-2 GEMM: h = x[N,128] @ W[128,128] ----------------
__global__ __launch_bounds__(256) void k_gemm_128(const float* __restrict__ x,
                                                  const float* __restrict__ W,
                                                  float* __restrict__ h, int N) {
    __shared__ float xs[16 * 128];
    int n0 = blockIdx.x * 16;
    int tid = threadIdx.x;
    for (int idx = tid; idx < 16 * 128; idx += 256) {
        int n = n0 + (idx >> 7);
        xs[idx] = (n < N) ? x[(size_t)n0 * 128 + idx] : 0.f;
    }
    __syncthreads();
    int j = tid & 127, g = tid >> 7;
    float acc[8];
#pragma unroll
    for (int i = 0; i < 8; ++i) acc[i] = 0.f;
    for (int k = 0; k < 128; ++k) {
        float w = W[k * 128 + j];
#pragma unroll
        for (int i = 0; i < 8; ++i) acc[i] += xs[(g * 8 + i) * 128 + k] * w;
    }
#pragma unroll
    for (int i = 0; i < 8; ++i) {
        int n = n0 + g * 8 + i;
        if (n < N) h[(size_t)n * 128 + j] = acc[i];
    }
}

// ---------------- edge MLP via MFMA + outputs ----------------
// Block: 64 edges, 4 waves. Wave: 16 edges x 128 hidden, K=256 (src|dst concat).
#define EB 64
__global__ __launch_bounds__(256) void k_edge_mfma(const ushort* __restrict__ xbf,
                                                   const ushort* __restrict__ Wt,
                                                   const float* __restrict__ lin1b,
                                                   const float* __restrict__ linfW,
                                                   const float* __restrict__ linfb,
                                                   const float* __restrict__ bboxes,
                                                   const int* __restrict__ bidx,
                                                   const int* __restrict__ row,
                                                   const int* __restrict__ col,
                                                   float* __restrict__ out_probs,
                                                   float* __restrict__ out_bbox,
                                                   float* __restrict__ out_bidx,
                                                   int E) {
    const int tid = threadIdx.x;
    const int wave = tid >> 6, lane = tid & 63;
    const int e0 = blockIdx.x * EB;
    const int m = lane & 15;       // A-row (edge) / B-col (hidden) lane index
    const int kb = lane >> 4;      // k sub-block 0..3

    const int e = e0 + wave * 16 + m;
    const int ec = (e < E) ? e : (E - 1);
    const int src = row[ec], dst = col[ec];

    f32x4 acc[8];
#pragma unroll
    for (int t = 0; t < 8; ++t) acc[t] = (f32x4){0.f, 0.f, 0.f, 0.f};

#pragma unroll
    for (int kk = 0; kk < 8; ++kk) {
        const int kloc = kk * 32 + kb * 8;           // global k of this lane's 8 elems
        const int node = (kloc < 128) ? src : dst;
        const int koff = kloc & 127;
        const short8 a = *reinterpret_cast<const short8*>(&xbf[(size_t)node * 128 + koff]);
#pragma unroll
        for (int t = 0; t < 8; ++t) {
            const short8 b = *reinterpret_cast<const short8*>(&Wt[(size_t)(t * 16 + m) * 256 + kloc]);
            acc[t] = __builtin_amdgcn_mfma_f32_16x16x32_bf16(a, b, acc[t], 0, 0, 0);
        }
    }

    // bias + relu in-register; partial logits over this lane's 8 hidden cols
    // C layout: col = lane&15 (+16*t), row = (lane>>4)*4 + r
    float p0[4] = {0.f, 0.f, 0.f, 0.f};   // class-0 partials per row
    float p1[4] = {0.f, 0.f, 0.f, 0.f};   // class-1 partials per row
#pragma unroll
    for (int t = 0; t < 8; ++t) {
        const int n = t * 16 + m;
        const float bn = lin1b[n];
        const float2 wf = *reinterpret_cast<const float2*>(&linfW[n * 2]);
#pragma unroll
        for (int r = 0; r < 4; ++r) {
            const float hv = fmaxf(acc[t][r] + bn, 0.f);
            p0[r] += hv * wf.x;
            p1[r] += hv * wf.y;
        }
    }
    // butterfly reduce across the 16 col-lanes (xor bits 0..3)
#pragma unroll
    for (int s = 1; s < 16; s <<= 1) {
#pragma unroll
        for (int r = 0; r < 4; ++r) {
            p0[r] += __shfl_xor(p0[r], s);
            p1[r] += __shfl_xor(p1[r], s);
        }
    }
    // lanes 0..3 of each 16-lane group write row r = lane&15
    if (m < 4) {
        const int er = e0 + wave * 16 + (kb << 2) + m;
        if (er < E) {
            const float z0 = p0[m] + linfb[0];
            const float z1 = p1[m] + linfb[1];
            const float mx = fmaxf(z0, z1);
            const float lse = mx + logf(expf(z0 - mx) + expf(z1 - mx));
            *reinterpret_cast<float2*>(&out_probs[(size_t)er * 2]) = make_float2(z0 - lse, z1 - lse);
        }
    }

    // bbox_pairs [E,8] and bbox_index_pairs [E,2]
    for (int idx = tid; idx < EB * 8; idx += 256) {
        const int ee = idx >> 3, q = idx & 7;
        const int e2 = e0 + ee;
        if (e2 < E) {
            const int node = (q < 4) ? row[e2] : col[e2];
            out_bbox[(size_t)e2 * 8 + q] = bboxes[(size_t)node * 4 + (q & 3)];
        }
    }
    for (int idx = tid; idx < EB * 2; idx += 256) {
        const int ee = idx >> 1, c = idx & 1;
        const int e2 = e0 + ee;
        if (e2 < E) {
            const int node = c ? col[e2] : row[e2];
            out_bidx[(size_t)e2 * 2 + c] = (float)bidx[node];
        }
    }
}

extern "C" void kernel_launch(void* const* d_in, const int* in_sizes, int n_in,
                              void* d_out, int out_size, void* d_ws, size_t ws_size,
                              hipStream_t stream) {
    const float* feat   = (const float*)d_in[0];
    const float* bboxes = (const float*)d_in[1];
    const int*   bidx   = (const int*)d_in[2];
    const int*   eidx   = (const int*)d_in[3];
    const float* W1     = (const float*)d_in[4];
    const float* b1     = (const float*)d_in[5];
    const float* W2     = (const float*)d_in[6];
    const float* b2     = (const float*)d_in[7];
    const float* lin1W  = (const float*)d_in[8];
    const float* lin1b  = (const float*)d_in[9];
    const float* linfW  = (const float*)d_in[10];
    const float* linfb  = (const float*)d_in[11];

    const int N = in_sizes[0] / 8;
    const int E = in_sizes[3] / 2;
    const int* row = eidx;        // sources
    const int* col = eidx + E;    // targets

    size_t Np = ((size_t)N + 255) & ~255ull;
    size_t Ep = ((size_t)E + 255) & ~255ull;
    int*    cnt    = (int*)d_ws;                 // Np
    int*    cursor = cnt + Np;                   // Np
    int*    ptr    = cursor + Np;                // Np+256
    float*  dinv   = (float*)(ptr + Np + 256);   // Np
    int*    esrc   = (int*)(dinv + Np);          // Ep
    float*  enorm  = (float*)(esrc + Ep);        // Ep
    float*  bufA   = enorm + Ep;                 // N*128 f32
    float*  bufB   = bufA + (size_t)N * 128;     // N*128 f32
    ushort* xbf    = (ushort*)(bufB + (size_t)N * 128);  // N*128 bf16
    ushort* Wt     = xbf + (size_t)N * 128;      // 128*256 bf16

    float* out       = (float*)d_out;
    float* out_probs = out;                   // E*2
    float* out_bbox  = out + (size_t)E * 2;   // E*8
    float* out_bidx  = out + (size_t)E * 10;  // E*2

    const int total = N * 128;
    const int B = 256;

    // CSR build + dinv + weight prep
    k_zero<<<(int)((2 * Np + B - 1) / B), B, 0, stream>>>(cnt, (int)(2 * Np));
    k_hist<<<(E + B - 1) / B, B, 0, stream>>>(col, cnt, E);
    k_scan<<<1, 1024, 0, stream>>>(cnt, ptr, N);
    k_dinv<<<(N + B - 1) / B, B, 0, stream>>>(cnt, dinv, N);
    k_fill<<<(E + B - 1) / B, B, 0, stream>>>(row, col, dinv, ptr, cursor, esrc, enorm, E);
    k_prepW<<<(128 * 256 + B - 1) / B, B, 0, stream>>>(lin1W, Wt);

    // layer 1
    k_gemm_f8<<<(total + B - 1) / B, B, 0, stream>>>(feat, W1, bufA, total);
    k_gather<<<(N + 7) / 8, B, 0, stream>>>(bufA, dinv, ptr, esrc, enorm, b1, bufB, N);

    // layer 2 (aggregate writes bf16 directly for the edge MLP)
    k_gemm_128<<<(N + 15) / 16, B, 0, stream>>>(bufB, W2, bufA, N);
    k_gather_bf<<<(N + 7) / 8, B, 0, stream>>>(bufA, dinv, ptr, esrc, enorm, b2, xbf, N);

    // edge MLP (MFMA) + outputs
    k_edge_mfma<<<(E + EB - 1) / EB, B, 0, stream>>>(xbf, Wt, lin1b, linfW, linfb,
                                                     bboxes, bidx, row, col,
                                                     out_probs, out_bbox, out_bidx, E);
}

// Round 5
// 446.075 us; speedup vs baseline: 9.1593x; 1.6810x over previous
//
#include <hip/hip_runtime.h>
#include <hip/hip_bf16.h>

// N=50000 nodes, E=800000 edges, D=128, F_IN=8, C=2
// Output float32: [probs E*2 | bbox_pairs E*8 | bbox_index_pairs E*2]

typedef __attribute__((ext_vector_type(8))) short short8;
typedef __attribute__((ext_vector_type(4))) float f32x4;

__device__ inline ushort f2bf(float f) {
    union { __hip_bfloat16 h; ushort u; } cv;
    cv.h = __float2bfloat16(f);
    return cv.u;
}

// ---------------- CSR build ----------------
__global__ void k_zero(int* __restrict__ p, int n) {
    int i = blockIdx.x * blockDim.x + threadIdx.x;
    if (i < n) p[i] = 0;
}

__global__ void k_hist(const int* __restrict__ col, int* __restrict__ cnt, int E) {
    int e = blockIdx.x * blockDim.x + threadIdx.x;
    if (e < E) atomicAdd(&cnt[col[e]], 1);
}

__global__ __launch_bounds__(1024) void k_scan(const int* __restrict__ cnt,
                                               int* __restrict__ ptr, int N) {
    __shared__ int sums[1024];
    int tid = threadIdx.x;
    int chunk = (N + 1023) / 1024;
    int lo = tid * chunk;
    int hi = min(lo + chunk, N);
    int s = 0;
    for (int i = lo; i < hi; ++i) s += cnt[i];
    sums[tid] = s;
    __syncthreads();
    for (int off = 1; off < 1024; off <<= 1) {
        int v = (tid >= off) ? sums[tid - off] : 0;
        __syncthreads();
        sums[tid] += v;
        __syncthreads();
    }
    int run = (tid > 0) ? sums[tid - 1] : 0;
    for (int i = lo; i < hi; ++i) { ptr[i] = run; run += cnt[i]; }
    if (tid == 1023) ptr[N] = run;
}

__global__ void k_dinv(const int* __restrict__ cnt, float* __restrict__ dinv, int n) {
    int i = blockIdx.x * blockDim.x + threadIdx.x;
    if (i < n) dinv[i] = rsqrtf(1.0f + (float)cnt[i]);
}

__global__ void k_fill(const int* __restrict__ row, const int* __restrict__ col,
                       const float* __restrict__ dinv, const int* __restrict__ ptr,
                       int* __restrict__ cursor, int* __restrict__ esrc,
                       float* __restrict__ enorm, int E) {
    int e = blockIdx.x * blockDim.x + threadIdx.x;
    if (e >= E) return;
    int r = row[e], c = col[e];
    int p = ptr[c] + atomicAdd(&cursor[c], 1);
    esrc[p] = r;
    enorm[p] = dinv[r] * dinv[c];
}

// ---------------- weight prep: Wt[n][k] = bf16(lin1W[k][n]) ----------------
__global__ void k_prepW(const float* __restrict__ W, ushort* __restrict__ Wt) {
    int tid = blockIdx.x * blockDim.x + threadIdx.x;
    if (tid >= 128 * 256) return;
    int n = tid >> 8, k = tid & 255;
    Wt[tid] = f2bf(W[k * 128 + n]);
}

// ---------------- layer-1 GEMM: h = feat[N,8] @ W1[8,128] ----------------
__global__ __launch_bounds__(256) void k_gemm_f8(const float* __restrict__ feat,
                                                 const float* __restrict__ W1,
                                                 float* __restrict__ h, int total) {
    int tid = blockIdx.x * blockDim.x + threadIdx.x;
    if (tid >= total) return;
    int n = tid >> 7, j = tid & 127;
    float acc = 0.f;
#pragma unroll
    for (int k = 0; k < 8; ++k) acc += feat[n * 8 + k] * W1[k * 128 + j];
    h[tid] = acc;
}

// ---------------- fused aggregate (fp32 out): relu(h[n]*dinv^2 + sum h[s]*norm + b) ----------------
__global__ __launch_bounds__(256) void k_gather(const float* __restrict__ h,
                                                const float* __restrict__ dinv,
                                                const int* __restrict__ ptr,
                                                const int* __restrict__ esrc,
                                                const float* __restrict__ enorm,
                                                const float* __restrict__ b,
                                                float* __restrict__ out, int N) {
    int g = threadIdx.x >> 5;
    int q = threadIdx.x & 31;
    int node = blockIdx.x * 8 + g;
    if (node >= N) return;
    float d = dinv[node];
    float4 acc = *reinterpret_cast<const float4*>(&h[(size_t)node * 128 + q * 4]);
    float dd = d * d;
    acc.x *= dd; acc.y *= dd; acc.z *= dd; acc.w *= dd;
    int i = ptr[node], end = ptr[node + 1];
    for (; i + 1 < end; i += 2) {
        int s0 = esrc[i], s1 = esrc[i + 1];
        float n0 = enorm[i], n1 = enorm[i + 1];
        const float4 v0 = *reinterpret_cast<const float4*>(&h[(size_t)s0 * 128 + q * 4]);
        const float4 v1 = *reinterpret_cast<const float4*>(&h[(size_t)s1 * 128 + q * 4]);
        acc.x += v0.x * n0 + v1.x * n1;
        acc.y += v0.y * n0 + v1.y * n1;
        acc.z += v0.z * n0 + v1.z * n1;
        acc.w += v0.w * n0 + v1.w * n1;
    }
    if (i < end) {
        int s0 = esrc[i];
        float n0 = enorm[i];
        const float4 v0 = *reinterpret_cast<const float4*>(&h[(size_t)s0 * 128 + q * 4]);
        acc.x += v0.x * n0; acc.y += v0.y * n0; acc.z += v0.z * n0; acc.w += v0.w * n0;
    }
    const float4 bb = *reinterpret_cast<const float4*>(&b[q * 4]);
    float4 r;
    r.x = fmaxf(acc.x + bb.x, 0.f);
    r.y = fmaxf(acc.y + bb.y, 0.f);
    r.z = fmaxf(acc.z + bb.z, 0.f);
    r.w = fmaxf(acc.w + bb.w, 0.f);
    *reinterpret_cast<float4*>(&out[(size_t)node * 128 + q * 4]) = r;
}

// ---------------- fused aggregate (bf16 out) ----------------
__global__ __launch_bounds__(256) void k_gather_bf(const float* __restrict__ h,
                                                   const float* __restrict__ dinv,
                                                   const int* __restrict__ ptr,
                                                   const int* __restrict__ esrc,
                                                   const float* __restrict__ enorm,
                                                   const float* __restrict__ b,
                                                   ushort* __restrict__ out, int N) {
    int g = threadIdx.x >> 5;
    int q = threadIdx.x & 31;
    int node = blockIdx.x * 8 + g;
    if (node >= N) return;
    float d = dinv[node];
    float4 acc = *reinterpret_cast<const float4*>(&h[(size_t)node * 128 + q * 4]);
    float dd = d * d;
    acc.x *= dd; acc.y *= dd; acc.z *= dd; acc.w *= dd;
    int i = ptr[node], end = ptr[node + 1];
    for (; i + 1 < end; i += 2) {
        int s0 = esrc[i], s1 = esrc[i + 1];
        float n0 = enorm[i], n1 = enorm[i + 1];
        const float4 v0 = *reinterpret_cast<const float4*>(&h[(size_t)s0 * 128 + q * 4]);
        const float4 v1 = *reinterpret_cast<const float4*>(&h[(size_t)s1 * 128 + q * 4]);
        acc.x += v0.x * n0 + v1.x * n1;
        acc.y += v0.y * n0 + v1.y * n1;
        acc.z += v0.z * n0 + v1.z * n1;
        acc.w += v0.w * n0 + v1.w * n1;
    }
    if (i < end) {
        int s0 = esrc[i];
        float n0 = enorm[i];
        const float4 v0 = *reinterpret_cast<const float4*>(&h[(size_t)s0 * 128 + q * 4]);
        acc.x += v0.x * n0; acc.y += v0.y * n0; acc.z += v0.z * n0; acc.w += v0.w * n0;
    }
    const float4 bb = *reinterpret_cast<const float4*>(&b[q * 4]);
    ushort4 r;
    r.x = f2bf(fmaxf(acc.x + bb.x, 0.f));
    r.y = f2bf(fmaxf(acc.y + bb.y, 0.f));
    r.z = f2bf(fmaxf(acc.z + bb.z, 0.f));
    r.w = f2bf(fmaxf(acc.w + bb.w, 0.f));
    *reinterpret_cast<ushort4*>(&out[(size_t)node * 128 + q * 4]) = r;
}

// ---------------- layer-2 GEMM: h = x[N,128] @ W[128,128] ----------------
__global__ __launch_bounds__(256) void k_gemm_128(const float* __restrict__ x,
                                                  const float* __restrict__ W,
                                                  float* __restrict__ h, int N) {
    __shared__ float xs[16 * 128];
    int n0 = blockIdx.x * 16;
    int tid = threadIdx.x;
    for (int idx = tid; idx < 16 * 128; idx += 256) {
        int n = n0 + (idx >> 7);
        xs[idx] = (n < N) ? x[(size_t)n0 * 128 + idx] : 0.f;
    }
    __syncthreads();
    int j = tid & 127, g = tid >> 7;
    float acc[8];
#pragma unroll
    for (int i = 0; i < 8; ++i) acc[i] = 0.f;
    for (int k = 0; k < 128; ++k) {
        float w = W[k * 128 + j];
#pragma unroll
        for (int i = 0; i < 8; ++i) acc[i] += xs[(g * 8 + i) * 128 + k] * w;
    }
#pragma unroll
    for (int i = 0; i < 8; ++i) {
        int n = n0 + g * 8 + i;
        if (n < N) h[(size_t)n * 128 + j] = acc[i];
    }
}

// ---------------- edge MLP via MFMA, LDS-staged weights ----------------
// Block: 512 threads = 8 waves, 128 edges. Wave: 16 edges x 128 hidden, K=256.
#define EB2 128
__global__ __launch_bounds__(512) void k_edge_mfma(const ushort* __restrict__ xbf,
                                                   const ushort* __restrict__ Wt,
                                                   const float* __restrict__ lin1b,
                                                   const float* __restrict__ linfW,
                                                   const float* __restrict__ linfb,
                                                   const float* __restrict__ bboxes,
                                                   const int* __restrict__ bidx,
                                                   const int* __restrict__ row,
                                                   const int* __restrict__ col,
                                                   float* __restrict__ out_probs,
                                                   float* __restrict__ out_bbox,
                                                   float* __restrict__ out_bidx,
                                                   int E) {
    __shared__ ushort ldsW[128 * 256];   // 64 KB, XOR-swizzled
    const int tid = threadIdx.x;
    const int wave = tid >> 6, lane = tid & 63;
    const int e0 = blockIdx.x * EB2;
    const int m = lane & 15;       // A-row (edge) / B-col (hidden) lane index
    const int kb = lane >> 4;      // k sub-block 0..3

    const int e = e0 + wave * 16 + m;
    const int ec = (e < E) ? e : (E - 1);
    const int src = row[ec], dst = col[ec];

    // Prefetch all 8 A-fragments (overlaps LDS staging + barrier)
    short8 a[8];
#pragma unroll
    for (int kk = 0; kk < 8; ++kk) {
        const int kloc = kk * 32 + kb * 8;
        const int node = (kloc < 128) ? src : dst;
        a[kk] = *reinterpret_cast<const short8*>(&xbf[(size_t)node * 128 + (kloc & 127)]);
    }

    // Stage Wt -> LDS with XOR swizzle (byte ^= ((row&7)<<4), row = n, 512B rows)
    {
        char* lb = reinterpret_cast<char*>(ldsW);
        const short8* wg = reinterpret_cast<const short8*>(Wt);
#pragma unroll
        for (int i = 0; i < 8; ++i) {
            const int g = i * 512 + tid;            // short8 index
            const int bo = g * 16;                  // byte offset
            const int swz = bo ^ ((bo >> 9 & 7) << 4);
            *reinterpret_cast<short8*>(lb + swz) = wg[g];
        }
    }
    __syncthreads();

    f32x4 acc[8];
#pragma unroll
    for (int t = 0; t < 8; ++t) acc[t] = (f32x4){0.f, 0.f, 0.f, 0.f};

    const char* lbr = reinterpret_cast<const char*>(ldsW);
    const int mswz = (m & 7) << 4;
#pragma unroll
    for (int kk = 0; kk < 8; ++kk) {
        const int kloc = kk * 32 + kb * 8;
#pragma unroll
        for (int t = 0; t < 8; ++t) {
            const int bo = ((t * 16 + m) * 256 + kloc) * 2;
            const short8 b = *reinterpret_cast<const short8*>(lbr + (bo ^ mswz));
            acc[t] = __builtin_amdgcn_mfma_f32_16x16x32_bf16(a[kk], b, acc[t], 0, 0, 0);
        }
    }

    // bias + relu in-register; partial logits over this lane's 8 hidden cols
    float p0[4] = {0.f, 0.f, 0.f, 0.f};
    float p1[4] = {0.f, 0.f, 0.f, 0.f};
#pragma unroll
    for (int t = 0; t < 8; ++t) {
        const int n = t * 16 + m;
        const float bn = lin1b[n];
        const float2 wf = *reinterpret_cast<const float2*>(&linfW[n * 2]);
#pragma unroll
        for (int r = 0; r < 4; ++r) {
            const float hv = fmaxf(acc[t][r] + bn, 0.f);
            p0[r] += hv * wf.x;
            p1[r] += hv * wf.y;
        }
    }
#pragma unroll
    for (int s = 1; s < 16; s <<= 1) {
#pragma unroll
        for (int r = 0; r < 4; ++r) {
            p0[r] += __shfl_xor(p0[r], s);
            p1[r] += __shfl_xor(p1[r], s);
        }
    }
    if (m < 4) {
        const int er = e0 + wave * 16 + (kb << 2) + m;
        if (er < E) {
            const float z0 = p0[m] + linfb[0];
            const float z1 = p1[m] + linfb[1];
            const float mx = fmaxf(z0, z1);
            const float lse = mx + logf(expf(z0 - mx) + expf(z1 - mx));
            *reinterpret_cast<float2*>(&out_probs[(size_t)er * 2]) = make_float2(z0 - lse, z1 - lse);
        }
    }

    // bbox_pairs [E,8] and bbox_index_pairs [E,2]
    for (int idx = tid; idx < EB2 * 8; idx += 512) {
        const int ee = idx >> 3, q = idx & 7;
        const int e2 = e0 + ee;
        if (e2 < E) {
            const int node = (q < 4) ? row[e2] : col[e2];
            out_bbox[(size_t)e2 * 8 + q] = bboxes[(size_t)node * 4 + (q & 3)];
        }
    }
    for (int idx = tid; idx < EB2 * 2; idx += 512) {
        const int ee = idx >> 1, c = idx & 1;
        const int e2 = e0 + ee;
        if (e2 < E) {
            const int node = c ? col[e2] : row[e2];
            out_bidx[(size_t)e2 * 2 + c] = (float)bidx[node];
        }
    }
}

extern "C" void kernel_launch(void* const* d_in, const int* in_sizes, int n_in,
                              void* d_out, int out_size, void* d_ws, size_t ws_size,
                              hipStream_t stream) {
    const float* feat   = (const float*)d_in[0];
    const float* bboxes = (const float*)d_in[1];
    const int*   bidx   = (const int*)d_in[2];
    const int*   eidx   = (const int*)d_in[3];
    const float* W1     = (const float*)d_in[4];
    const float* b1     = (const float*)d_in[5];
    const float* W2     = (const float*)d_in[6];
    const float* b2     = (const float*)d_in[7];
    const float* lin1W  = (const float*)d_in[8];
    const float* lin1b  = (const float*)d_in[9];
    const float* linfW  = (const float*)d_in[10];
    const float* linfb  = (const float*)d_in[11];

    const int N = in_sizes[0] / 8;
    const int E = in_sizes[3] / 2;
    const int* row = eidx;        // sources
    const int* col = eidx + E;    // targets

    size_t Np = ((size_t)N + 255) & ~255ull;
    size_t Ep = ((size_t)E + 255) & ~255ull;
    int*    cnt    = (int*)d_ws;                 // Np
    int*    cursor = cnt + Np;                   // Np
    int*    ptr    = cursor + Np;                // Np+256
    float*  dinv   = (float*)(ptr + Np + 256);   // Np
    int*    esrc   = (int*)(dinv + Np);          // Ep
    float*  enorm  = (float*)(esrc + Ep);        // Ep
    float*  bufA   = enorm + Ep;                 // N*128 f32
    float*  bufB   = bufA + (size_t)N * 128;     // N*128 f32
    ushort* xbf    = (ushort*)(bufB + (size_t)N * 128);  // N*128 bf16
    ushort* Wt     = xbf + (size_t)N * 128;      // 128*256 bf16

    float* out       = (float*)d_out;
    float* out_probs = out;                   // E*2
    float* out_bbox  = out + (size_t)E * 2;   // E*8
    float* out_bidx  = out + (size_t)E * 10;  // E*2

    const int total = N * 128;
    const int B = 256;

    // CSR build + dinv + weight prep
    k_zero<<<(int)((2 * Np + B - 1) / B), B, 0, stream>>>(cnt, (int)(2 * Np));
    k_hist<<<(E + B - 1) / B, B, 0, stream>>>(col, cnt, E);
    k_scan<<<1, 1024, 0, stream>>>(cnt, ptr, N);
    k_dinv<<<(N + B - 1) / B, B, 0, stream>>>(cnt, dinv, N);
    k_fill<<<(E + B - 1) / B, B, 0, stream>>>(row, col, dinv, ptr, cursor, esrc, enorm, E);
    k_prepW<<<(128 * 256 + B - 1) / B, B, 0, stream>>>(lin1W, Wt);

    // layer 1
    k_gemm_f8<<<(total + B - 1) / B, B, 0, stream>>>(feat, W1, bufA, total);
    k_gather<<<(N + 7) / 8, B, 0, stream>>>(bufA, dinv, ptr, esrc, enorm, b1, bufB, N);

    // layer 2 (aggregate writes bf16 directly for the edge MLP)
    k_gemm_128<<<(N + 15) / 16, B, 0, stream>>>(bufB, W2, bufA, N);
    k_gather_bf<<<(N + 7) / 8, B, 0, stream>>>(bufA, dinv, ptr, esrc, enorm, b2, xbf, N);

    // edge MLP (MFMA, LDS weights) + outputs
    k_edge_mfma<<<(E + EB2 - 1) / EB2, 512, 0, stream>>>(xbf, Wt, lin1b, linfW, linfb,
                                                         bboxes, bidx, row, col,
                                                         out_probs, out_bbox, out_bidx, E);
}

// Round 6
// 355.210 us; speedup vs baseline: 11.5023x; 1.2558x over previous
//
#include <hip/hip_runtime.h>
#include <hip/hip_bf16.h>

// N=50000 nodes, E=800000 edges, D=128, F_IN=8, C=2
// Output float32: [probs E*2 | bbox_pairs E*8 | bbox_index_pairs E*2]

typedef __attribute__((ext_vector_type(8))) short short8;
typedef __attribute__((ext_vector_type(4))) float f32x4;

__device__ inline ushort f2bf(float f) {
    union { __hip_bfloat16 h; ushort u; } cv;
    cv.h = __float2bfloat16(f);
    return cv.u;
}
__device__ inline float bf2f(ushort u) {
    union { float f; uint u; } c;
    c.u = ((uint)u) << 16;
    return c.f;
}

// ---------------- CSR build ----------------
__global__ void k_zero(int* __restrict__ p, int n) {
    int i = blockIdx.x * blockDim.x + threadIdx.x;
    if (i < n) p[i] = 0;
}

__global__ void k_hist(const int* __restrict__ col, int* __restrict__ cnt, int E) {
    int e = blockIdx.x * blockDim.x + threadIdx.x;
    if (e < E) atomicAdd(&cnt[col[e]], 1);
}

__global__ __launch_bounds__(1024) void k_scan(const int* __restrict__ cnt,
                                               int* __restrict__ ptr, int N) {
    __shared__ int sums[1024];
    int tid = threadIdx.x;
    int chunk = (N + 1023) / 1024;
    int lo = tid * chunk;
    int hi = min(lo + chunk, N);
    int s = 0;
    for (int i = lo; i < hi; ++i) s += cnt[i];
    sums[tid] = s;
    __syncthreads();
    for (int off = 1; off < 1024; off <<= 1) {
        int v = (tid >= off) ? sums[tid - off] : 0;
        __syncthreads();
        sums[tid] += v;
        __syncthreads();
    }
    int run = (tid > 0) ? sums[tid - 1] : 0;
    for (int i = lo; i < hi; ++i) { ptr[i] = run; run += cnt[i]; }
    if (tid == 1023) ptr[N] = run;
}

__global__ void k_dinv(const int* __restrict__ cnt, float* __restrict__ dinv, int n) {
    int i = blockIdx.x * blockDim.x + threadIdx.x;
    if (i < n) dinv[i] = rsqrtf(1.0f + (float)cnt[i]);
}

__global__ void k_fill(const int* __restrict__ row, const int* __restrict__ col,
                       const float* __restrict__ dinv, const int* __restrict__ ptr,
                       int* __restrict__ cursor, int* __restrict__ esrc,
                       float* __restrict__ enorm, int E) {
    int e = blockIdx.x * blockDim.x + threadIdx.x;
    if (e >= E) return;
    int r = row[e], c = col[e];
    int p = ptr[c] + atomicAdd(&cursor[c], 1);
    esrc[p] = r;
    enorm[p] = dinv[r] * dinv[c];
}

// ---------------- weight prep ----------------
// Wt[n][k] = bf16(lin1W[k][n]), n<128, k<256
__global__ void k_prepW(const float* __restrict__ W, ushort* __restrict__ Wt) {
    int tid = blockIdx.x * blockDim.x + threadIdx.x;
    if (tid >= 128 * 256) return;
    int n = tid >> 8, k = tid & 255;
    Wt[tid] = f2bf(W[k * 128 + n]);
}
// W2t[n][k] = bf16(W2[k][n]), n<128, k<128
__global__ void k_prepW2(const float* __restrict__ W, ushort* __restrict__ Wt) {
    int tid = blockIdx.x * blockDim.x + threadIdx.x;
    if (tid >= 128 * 128) return;
    int n = tid >> 7, k = tid & 127;
    Wt[tid] = f2bf(W[k * 128 + n]);
}

// ---------------- layer-1 aggregate on raw features [N,8] ----------------
// aggF[n] = feat[n]*dinv[n]^2 + sum_in feat[s]*norm   (8 lanes per node)
__global__ __launch_bounds__(256) void k_agg8(const float* __restrict__ feat,
                                              const float* __restrict__ dinv,
                                              const int* __restrict__ ptr,
                                              const int* __restrict__ esrc,
                                              const float* __restrict__ enorm,
                                              float* __restrict__ aggF, int N) {
    int lane8 = threadIdx.x & 7;
    int node = blockIdx.x * 32 + (threadIdx.x >> 3);
    if (node >= N) return;
    float d = dinv[node];
    float acc = feat[(size_t)node * 8 + lane8] * d * d;
    int i = ptr[node], end = ptr[node + 1];
    for (; i < end; ++i) {
        acc += feat[(size_t)esrc[i] * 8 + lane8] * enorm[i];
    }
    aggF[(size_t)node * 8 + lane8] = acc;
}

// ---------------- layer-1 GEMM: x1 = bf16(relu(aggF[N,8] @ W1 + b1)) ----------------
__global__ __launch_bounds__(256) void k_gemm1(const float* __restrict__ aggF,
                                               const float* __restrict__ W1,
                                               const float* __restrict__ b1,
                                               ushort* __restrict__ x1, int total) {
    int tid = blockIdx.x * blockDim.x + threadIdx.x;
    if (tid >= total) return;
    int n = tid >> 7, j = tid & 127;
    float acc = b1[j];
#pragma unroll
    for (int k = 0; k < 8; ++k) acc += aggF[(size_t)n * 8 + k] * W1[k * 128 + j];
    x1[tid] = f2bf(fmaxf(acc, 0.f));
}

// ---------------- layer-2 GEMM via MFMA: h2 = x1[N,128] @ W2 (bf16 out, no bias) ----------------
// Block: 256 thr = 4 waves, 64 nodes. Wave: 16 nodes x 128 cols, K=128.
__global__ __launch_bounds__(256) void k_gemm2(const ushort* __restrict__ x1,
                                               const ushort* __restrict__ W2t,
                                               ushort* __restrict__ h2, int N) {
    __shared__ ushort ldsW[128 * 128];   // 32 KB, XOR-swizzled (256B rows)
    const int tid = threadIdx.x;
    const int wave = tid >> 6, lane = tid & 63;
    const int m = lane & 15, kb = lane >> 4;
    const int n0 = blockIdx.x * 64;

    const int node_a = min(n0 + wave * 16 + m, N - 1);
    short8 a[4];
#pragma unroll
    for (int kk = 0; kk < 4; ++kk) {
        a[kk] = *reinterpret_cast<const short8*>(&x1[(size_t)node_a * 128 + kk * 32 + kb * 8]);
    }

    {
        char* lb = reinterpret_cast<char*>(ldsW);
        const short8* wg = reinterpret_cast<const short8*>(W2t);
#pragma unroll
        for (int i = 0; i < 8; ++i) {
            const int g = i * 256 + tid;
            const int bo = g * 16;
            const int swz = bo ^ (((bo >> 8) & 7) << 4);
            *reinterpret_cast<short8*>(lb + swz) = wg[g];
        }
    }
    __syncthreads();

    f32x4 acc[8];
#pragma unroll
    for (int t = 0; t < 8; ++t) acc[t] = (f32x4){0.f, 0.f, 0.f, 0.f};

    const char* lbr = reinterpret_cast<const char*>(ldsW);
    const int mswz = (m & 7) << 4;
#pragma unroll
    for (int kk = 0; kk < 4; ++kk) {
#pragma unroll
        for (int t = 0; t < 8; ++t) {
            const int bo = (t * 16 + m) * 256 + kk * 64 + kb * 16;
            const short8 b = *reinterpret_cast<const short8*>(lbr + (bo ^ mswz));
            acc[t] = __builtin_amdgcn_mfma_f32_16x16x32_bf16(a[kk], b, acc[t], 0, 0, 0);
        }
    }

    // C layout: col = t*16 + m, row(node) = kb*4 + r
#pragma unroll
    for (int r = 0; r < 4; ++r) {
        const int node = n0 + wave * 16 + kb * 4 + r;
        if (node < N) {
#pragma unroll
            for (int t = 0; t < 8; ++t) {
                h2[(size_t)node * 128 + t * 16 + m] = f2bf(acc[t][r]);
            }
        }
    }
}

// ---------------- layer-2 aggregate (bf16 rows): xbf = bf16(relu(A~ h2 + b2)) ----------------
// 16 lanes per node, short8 per lane.
__global__ __launch_bounds__(256) void k_gather2(const ushort* __restrict__ h2,
                                                 const float* __restrict__ dinv,
                                                 const int* __restrict__ ptr,
                                                 const int* __restrict__ esrc,
                                                 const float* __restrict__ enorm,
                                                 const float* __restrict__ b2,
                                                 ushort* __restrict__ xbf, int N) {
    int lane16 = threadIdx.x & 15;
    int node = blockIdx.x * 16 + (threadIdx.x >> 4);
    if (node >= N) return;
    float d = dinv[node];
    float dd = d * d;
    float acc[8];
    {
        const short8 v = *reinterpret_cast<const short8*>(&h2[(size_t)node * 128 + lane16 * 8]);
#pragma unroll
        for (int i = 0; i < 8; ++i) acc[i] = bf2f((ushort)v[i]) * dd;
    }
    int i = ptr[node], end = ptr[node + 1];
    for (; i < end; ++i) {
        const int s = esrc[i];
        const float nm = enorm[i];
        const short8 v = *reinterpret_cast<const short8*>(&h2[(size_t)s * 128 + lane16 * 8]);
#pragma unroll
        for (int q = 0; q < 8; ++q) acc[q] += bf2f((ushort)v[q]) * nm;
    }
    short8 r;
#pragma unroll
    for (int q = 0; q < 8; ++q) {
        r[q] = (short)f2bf(fmaxf(acc[q] + b2[lane16 * 8 + q], 0.f));
    }
    *reinterpret_cast<short8*>(&xbf[(size_t)node * 128 + lane16 * 8]) = r;
}

// ---------------- edge MLP via MFMA, LDS-staged weights ----------------
// Block: 512 threads = 8 waves, 128 edges. Wave: 16 edges x 128 hidden, K=256.
#define EB2 128
__global__ __launch_bounds__(512) void k_edge_mfma(const ushort* __restrict__ xbf,
                                                   const ushort* __restrict__ Wt,
                                                   const float* __restrict__ lin1b,
                                                   const float* __restrict__ linfW,
                                                   const float* __restrict__ linfb,
                                                   const float* __restrict__ bboxes,
                                                   const int* __restrict__ bidx,
                                                   const int* __restrict__ row,
                                                   const int* __restrict__ col,
                                                   float* __restrict__ out_probs,
                                                   float* __restrict__ out_bbox,
                                                   float* __restrict__ out_bidx,
                                                   int E) {
    __shared__ ushort ldsW[128 * 256];   // 64 KB, XOR-swizzled (512B rows)
    const int tid = threadIdx.x;
    const int wave = tid >> 6, lane = tid & 63;
    const int e0 = blockIdx.x * EB2;
    const int m = lane & 15;
    const int kb = lane >> 4;

    const int e = e0 + wave * 16 + m;
    const int ec = (e < E) ? e : (E - 1);
    const int src = row[ec], dst = col[ec];

    short8 a[8];
#pragma unroll
    for (int kk = 0; kk < 8; ++kk) {
        const int kloc = kk * 32 + kb * 8;
        const int node = (kloc < 128) ? src : dst;
        a[kk] = *reinterpret_cast<const short8*>(&xbf[(size_t)node * 128 + (kloc & 127)]);
    }

    {
        char* lb = reinterpret_cast<char*>(ldsW);
        const short8* wg = reinterpret_cast<const short8*>(Wt);
#pragma unroll
        for (int i = 0; i < 8; ++i) {
            const int g = i * 512 + tid;
            const int bo = g * 16;
            const int swz = bo ^ (((bo >> 9) & 7) << 4);
            *reinterpret_cast<short8*>(lb + swz) = wg[g];
        }
    }
    __syncthreads();

    f32x4 acc[8];
#pragma unroll
    for (int t = 0; t < 8; ++t) acc[t] = (f32x4){0.f, 0.f, 0.f, 0.f};

    const char* lbr = reinterpret_cast<const char*>(ldsW);
    const int mswz = (m & 7) << 4;
#pragma unroll
    for (int kk = 0; kk < 8; ++kk) {
        const int kloc = kk * 32 + kb * 8;
#pragma unroll
        for (int t = 0; t < 8; ++t) {
            const int bo = ((t * 16 + m) * 256 + kloc) * 2;
            const short8 b = *reinterpret_cast<const short8*>(lbr + (bo ^ mswz));
            acc[t] = __builtin_amdgcn_mfma_f32_16x16x32_bf16(a[kk], b, acc[t], 0, 0, 0);
        }
    }

    float p0[4] = {0.f, 0.f, 0.f, 0.f};
    float p1[4] = {0.f, 0.f, 0.f, 0.f};
#pragma unroll
    for (int t = 0; t < 8; ++t) {
        const int n = t * 16 + m;
        const float bn = lin1b[n];
        const float2 wf = *reinterpret_cast<const float2*>(&linfW[n * 2]);
#pragma unroll
        for (int r = 0; r < 4; ++r) {
            const float hv = fmaxf(acc[t][r] + bn, 0.f);
            p0[r] += hv * wf.x;
            p1[r] += hv * wf.y;
        }
    }
#pragma unroll
    for (int s = 1; s < 16; s <<= 1) {
#pragma unroll
        for (int r = 0; r < 4; ++r) {
            p0[r] += __shfl_xor(p0[r], s);
            p1[r] += __shfl_xor(p1[r], s);
        }
    }
    if (m < 4) {
        const int er = e0 + wave * 16 + (kb << 2) + m;
        if (er < E) {
            const float z0 = p0[m] + linfb[0];
            const float z1 = p1[m] + linfb[1];
            const float mx = fmaxf(z0, z1);
            const float lse = mx + logf(expf(z0 - mx) + expf(z1 - mx));
            *reinterpret_cast<float2*>(&out_probs[(size_t)er * 2]) = make_float2(z0 - lse, z1 - lse);
        }
    }

    for (int idx = tid; idx < EB2 * 8; idx += 512) {
        const int ee = idx >> 3, q = idx & 7;
        const int e2 = e0 + ee;
        if (e2 < E) {
            const int node = (q < 4) ? row[e2] : col[e2];
            out_bbox[(size_t)e2 * 8 + q] = bboxes[(size_t)node * 4 + (q & 3)];
        }
    }
    for (int idx = tid; idx < EB2 * 2; idx += 512) {
        const int ee = idx >> 1, c = idx & 1;
        const int e2 = e0 + ee;
        if (e2 < E) {
            const int node = c ? col[e2] : row[e2];
            out_bidx[(size_t)e2 * 2 + c] = (float)bidx[node];
        }
    }
}

extern "C" void kernel_launch(void* const* d_in, const int* in_sizes, int n_in,
                              void* d_out, int out_size, void* d_ws, size_t ws_size,
                              hipStream_t stream) {
    const float* feat   = (const float*)d_in[0];
    const float* bboxes = (const float*)d_in[1];
    const int*   bidx   = (const int*)d_in[2];
    const int*   eidx   = (const int*)d_in[3];
    const float* W1     = (const float*)d_in[4];
    const float* b1     = (const float*)d_in[5];
    const float* W2     = (const float*)d_in[6];
    const float* b2     = (const float*)d_in[7];
    const float* lin1W  = (const float*)d_in[8];
    const float* lin1b  = (const float*)d_in[9];
    const float* linfW  = (const float*)d_in[10];
    const float* linfb  = (const float*)d_in[11];

    const int N = in_sizes[0] / 8;
    const int E = in_sizes[3] / 2;
    const int* row = eidx;        // sources
    const int* col = eidx + E;    // targets

    size_t Np = ((size_t)N + 255) & ~255ull;
    size_t Ep = ((size_t)E + 255) & ~255ull;
    size_t A8 = (((size_t)N * 8) + 255) & ~255ull;
    int*    cnt    = (int*)d_ws;                 // Np
    int*    cursor = cnt + Np;                   // Np
    int*    ptr    = cursor + Np;                // Np+256
    float*  dinv   = (float*)(ptr + Np + 256);   // Np
    int*    esrc   = (int*)(dinv + Np);          // Ep
    float*  enorm  = (float*)(esrc + Ep);        // Ep
    float*  aggF   = enorm + Ep;                 // A8 f32
    ushort* x1     = (ushort*)(aggF + A8);       // N*128 bf16
    ushort* h2     = x1 + (size_t)N * 128;       // N*128 bf16
    ushort* xbf    = h2 + (size_t)N * 128;       // N*128 bf16
    ushort* Wt     = xbf + (size_t)N * 128;      // 128*256 bf16
    ushort* W2t    = Wt + 128 * 256;             // 128*128 bf16

    float* out       = (float*)d_out;
    float* out_probs = out;                   // E*2
    float* out_bbox  = out + (size_t)E * 2;   // E*8
    float* out_bidx  = out + (size_t)E * 10;  // E*2

    const int total = N * 128;
    const int B = 256;

    // CSR build + dinv + weight prep
    k_zero<<<(int)((2 * Np + B - 1) / B), B, 0, stream>>>(cnt, (int)(2 * Np));
    k_hist<<<(E + B - 1) / B, B, 0, stream>>>(col, cnt, E);
    k_scan<<<1, 1024, 0, stream>>>(cnt, ptr, N);
    k_dinv<<<(N + B - 1) / B, B, 0, stream>>>(cnt, dinv, N);
    k_fill<<<(E + B - 1) / B, B, 0, stream>>>(row, col, dinv, ptr, cursor, esrc, enorm, E);
    k_prepW<<<(128 * 256 + B - 1) / B, B, 0, stream>>>(lin1W, Wt);
    k_prepW2<<<(128 * 128 + B - 1) / B, B, 0, stream>>>(W2, W2t);

    // layer 1 (aggregate-first on [N,8], then tiny GEMM)
    k_agg8<<<(N + 31) / 32, B, 0, stream>>>(feat, dinv, ptr, esrc, enorm, aggF, N);
    k_gemm1<<<(total + B - 1) / B, B, 0, stream>>>(aggF, W1, b1, x1, total);

    // layer 2 (MFMA GEMM, then bf16 gather)
    k_gemm2<<<(N + 63) / 64, B, 0, stream>>>(x1, W2t, h2, N);
    k_gather2<<<(N + 15) / 16, B, 0, stream>>>(h2, dinv, ptr, esrc, enorm, b2, xbf, N);

    // edge MLP (MFMA, LDS weights) + outputs
    k_edge_mfma<<<(E + EB2 - 1) / EB2, 512, 0, stream>>>(xbf, Wt, lin1b, linfW, linfb,
                                                         bboxes, bidx, row, col,
                                                         out_probs, out_bbox, out_bidx, E);
}